// Round 4
// baseline (603.695 us; speedup 1.0000x reference)
//
#include <hip/hip_runtime.h>

#define CC   256
#define HH   56
#define WWID 56
#define KIN1 1608
#define KP1  1632
#define NO1  72
#define NO2  288
#define PPB  16
#define H2   112
#define W2D  112

typedef unsigned short u16;
typedef unsigned int   u32;
typedef __attribute__((ext_vector_type(8))) short v8s;
typedef __attribute__((ext_vector_type(4))) float v4f;

#define W1BF_ELEMS (80 * KP1)
#define W2BF_OFF_B 262144

// LDS layout (bytes). Total 39392 -> 4 blocks/CU.
#define LDS_TOTAL 39392
#define OFF_ROW 0       // rowmaxT u16[16][776] (24832); aliased later: partials f32 (20480) -> y2L f32[16][296] (18944) -> tile f32[32][258] (33024)
#define OFF_COL 24832   // colmaxT u16[18][264] (9504)
#define OFF_X1  34336   // x1T / y1b u16[16][104] (3328)
#define OFF_GMX 37664   // gmax_s f32[8][3][18] (1728)

__device__ __forceinline__ u16 f2b(float x) {
  u32 u = __float_as_uint(x);
  u = (u + 0x7FFFu + ((u >> 16) & 1u)) >> 16;   // RNE fp32->bf16
  return (u16)u;
}

// ---- weight conversion; W1 columns PERMUTED to K-layout:
//   phys [0,768)    = x2 region: kj*256 + c      <- orig 72 + c*3 + kj
//   phys [768,1536) = x3 region: r*256 + c       <- orig 840 + c*3 + r
//   phys [1536,1632)= x1 region: m72 (<72), pad  <- orig m72
__global__ void kConvW(const float* __restrict__ W1, const float* __restrict__ W2,
                       u16* __restrict__ w1bf, u16* __restrict__ w2bf) {
  int idx = blockIdx.x * 256 + threadIdx.x;
  if (idx < W1BF_ELEMS) {
    int m = idx / KP1, k = idx - m * KP1;
    float v = 0.f;
    if (m < NO1) {
      int orig = -1;
      if (k < 768)                 orig = 72 + (k & 255) * 3 + (k >> 8);
      else if (k < 1536)           orig = 840 + (k & 255) * 3 + ((k - 768) >> 8);
      else if ((k - 1536) < NO1)   orig = k - 1536;
      if (orig >= 0) v = W1[m * KIN1 + orig];
    }
    w1bf[idx] = f2b(v);
  } else {
    int i2 = idx - W1BF_ELEMS;
    if (i2 < NO2 * 96) {
      int m = i2 / 96, k = i2 - m * 96;
      w2bf[i2] = (k < NO1) ? f2b(W2[m * NO1 + k]) : (u16)0;
    }
  }
}

__global__ __launch_bounds__(256) __attribute__((amdgpu_waves_per_eu(4, 4)))
void kFused(const float* __restrict__ in, const u16* __restrict__ w1bf,
            const float* __restrict__ b1, const u16* __restrict__ w2bf,
            const float* __restrict__ b2, float* __restrict__ out) {
  __shared__ __align__(16) char lds[LDS_TOTAL];
  u16*   rowmaxT = (u16*)(lds + OFF_ROW);
  u16*   colmaxT = (u16*)(lds + OFF_COL);
  u16*   x1T     = (u16*)(lds + OFF_X1);   // later aliased as y1b
  float* gmax_s  = (float*)(lds + OFF_GMX);
  float* partA   = (float*)lds;            // partials, then y2L, then tile
  float* y2L     = (float*)lds;
  float* tile    = (float*)lds;            // [32 x][258 c] f32

  const int t  = threadIdx.x;
  const int jt = blockIdx.x, i = blockIdx.y, b = blockIdx.z;
  const int g  = t >> 5;
  const int w  = t >> 6, lane = t & 63;
  const int ml = lane & 15, quad = lane >> 4;

  // zero x1T pad cols [72,96) for all 16 rows (192 u32)
  if (t < 192) {
    u32* xu = (u32*)x1T;   // row stride 52 u32
    xu[(t / 12) * 52 + 36 + (t % 12)] = 0u;
  }

  // ---------------- P1: per-channel window load + maxes ----------------
  const float* rowbase0 = in + ((size_t)b * CC + t) * (HH * WWID);
  u32 win_p[3][9];
  float colmax[18];
#pragma unroll
  for (int k = 0; k < 18; ++k) colmax[k] = -3.0e38f;

#pragma unroll
  for (int r = 0; r < 3; ++r) {
    const int row = i - 1 + r;
    float sc[18];
    if (row < 0 || row >= HH) {
#pragma unroll
      for (int k = 0; k < 18; ++k) sc[k] = 0.f;
    } else {
      const float* rp = rowbase0 + row * WWID;
      if (jt == 0) {
        float l[20];
        const float4 a0 = *(const float4*)(rp),      a1 = *(const float4*)(rp + 4),
                     a2 = *(const float4*)(rp + 8),  a3 = *(const float4*)(rp + 12),
                     a4 = *(const float4*)(rp + 16);
        l[0]=a0.x;l[1]=a0.y;l[2]=a0.z;l[3]=a0.w; l[4]=a1.x;l[5]=a1.y;l[6]=a1.z;l[7]=a1.w;
        l[8]=a2.x;l[9]=a2.y;l[10]=a2.z;l[11]=a2.w; l[12]=a3.x;l[13]=a3.y;l[14]=a3.z;l[15]=a3.w;
        l[16]=a4.x;l[17]=a4.y;l[18]=a4.z;l[19]=a4.w;
        sc[0] = 0.f;
#pragma unroll
        for (int k = 1; k < 18; ++k) sc[k] = l[k - 1];
      } else if (jt == 3) {
        float l[12];
        const float4 a0 = *(const float4*)(rp + 44), a1 = *(const float4*)(rp + 48),
                     a2 = *(const float4*)(rp + 52);
        l[0]=a0.x;l[1]=a0.y;l[2]=a0.z;l[3]=a0.w; l[4]=a1.x;l[5]=a1.y;l[6]=a1.z;l[7]=a1.w;
        l[8]=a2.x;l[9]=a2.y;l[10]=a2.z;l[11]=a2.w;
#pragma unroll
        for (int k = 0; k < 18; ++k) sc[k] = (k <= 8) ? l[k + 3] : 0.f;
      } else {
        float l[24];
        const float* q = rp + ((jt == 1) ? 12 : 28);
        const float4 a0 = *(const float4*)(q),      a1 = *(const float4*)(q + 4),
                     a2 = *(const float4*)(q + 8),  a3 = *(const float4*)(q + 12),
                     a4 = *(const float4*)(q + 16), a5 = *(const float4*)(q + 20);
        l[0]=a0.x;l[1]=a0.y;l[2]=a0.z;l[3]=a0.w; l[4]=a1.x;l[5]=a1.y;l[6]=a1.z;l[7]=a1.w;
        l[8]=a2.x;l[9]=a2.y;l[10]=a2.z;l[11]=a2.w; l[12]=a3.x;l[13]=a3.y;l[14]=a3.z;l[15]=a3.w;
        l[16]=a4.x;l[17]=a4.y;l[18]=a4.z;l[19]=a4.w; l[20]=a5.x;l[21]=a5.y;l[22]=a5.z;l[23]=a5.w;
#pragma unroll
        for (int k = 0; k < 18; ++k) sc[k] = l[k + 3];
      }
    }
    // x2 source: colmax accumulate over window rows
#pragma unroll
    for (int k = 0; k < 18; ++k) colmax[k] = fmaxf(colmax[k], sc[k]);
    // x3: sliding max over dj, bf16, [n][r*256+c]
#pragma unroll
    for (int n = 0; n < 16; ++n)
      rowmaxT[n * 776 + r * 256 + t] = f2b(fmaxf(fmaxf(sc[n], sc[n + 1]), sc[n + 2]));
    // x1: 32-channel group max per staged col
#pragma unroll
    for (int col = 0; col < 18; ++col) {
      float m = sc[col];
      m = fmaxf(m, __shfl_xor(m, 1));
      m = fmaxf(m, __shfl_xor(m, 2));
      m = fmaxf(m, __shfl_xor(m, 4));
      m = fmaxf(m, __shfl_xor(m, 8));
      m = fmaxf(m, __shfl_xor(m, 16));
      if ((t & 31) == col) gmax_s[g * 54 + r * 18 + col] = m;
    }
    // pack window row (bf16 pairs) for P7
#pragma unroll
    for (int k = 0; k < 9; ++k)
      win_p[r][k] = (u32)f2b(sc[2 * k]) | ((u32)f2b(sc[2 * k + 1]) << 16);
  }
#pragma unroll
  for (int col = 0; col < 18; ++col)
    colmaxT[col * 264 + t] = f2b(colmax[col]);
  // x1T scatter: each wave scatters its own 2 groups (g = 2w, 2w+1)
  asm volatile("s_waitcnt lgkmcnt(0)" ::: "memory");
#pragma unroll
  for (int rep = 0; rep < 5; ++rep) {
    int idx = lane + 64 * rep;
    if (idx < 288) {
      int gl = idx / 144, rem = idx - gl * 144;
      int n = rem / 9, r9 = rem - n * 9, ki = r9 / 3, kj = r9 - ki * 3;
      int gg = 2 * w + gl;
      x1T[n * 104 + gg * 9 + r9] = f2b(gmax_s[gg * 54 + ki * 18 + n + kj]);
    }
  }
  __syncthreads();

  // ---------------- P2: conv1 MFMA, waves split K (13/13/13/12) ----------------
  v4f acc[5];
#pragma unroll
  for (int mt = 0; mt < 5; ++mt) acc[mt] = (v4f){0.f, 0.f, 0.f, 0.f};
  const int ks0 = w * 13, ks1 = (w == 3) ? 51 : ks0 + 13;

  auto loadB = [&](int ks) -> v8s {
    if (ks < 24) {
      int kj = ks >> 3, c0 = (ks & 7) * 32;
      return *(v8s*)&colmaxT[(ml + kj) * 264 + c0 + quad * 8];
    } else if (ks < 48) {
      return *(v8s*)&rowmaxT[ml * 776 + (ks - 24) * 32 + quad * 8];
    } else {
      return *(v8s*)&x1T[ml * 104 + (ks - 48) * 32 + quad * 8];
    }
  };

  {
    v8s bf_c = loadB(ks0);
    v8s af_c[5];
    {
      const int k0 = ks0 * 32 + quad * 8;
#pragma unroll
      for (int mt = 0; mt < 5; ++mt)
        af_c[mt] = *(const v8s*)&w1bf[(mt * 16 + ml) * KP1 + k0];
    }
    for (int ks = ks0; ks < ks1; ++ks) {
      v8s bf_n, af_n[5];
      if (ks + 1 < ks1) {
        bf_n = loadB(ks + 1);
        const int k0n = (ks + 1) * 32 + quad * 8;
#pragma unroll
        for (int mt = 0; mt < 5; ++mt)
          af_n[mt] = *(const v8s*)&w1bf[(mt * 16 + ml) * KP1 + k0n];
      }
#pragma unroll
      for (int mt = 0; mt < 5; ++mt)
        acc[mt] = __builtin_amdgcn_mfma_f32_16x16x32_bf16(af_c[mt], bf_c, acc[mt], 0, 0, 0);
      if (ks + 1 < ks1) {
        bf_c = bf_n;
#pragma unroll
        for (int mt = 0; mt < 5; ++mt) af_c[mt] = af_n[mt];
      }
    }
  }
  __syncthreads();

  // ---------------- P3: partials to LDS (alias rowmaxT) ----------------
#pragma unroll
  for (int mt = 0; mt < 5; ++mt)
    *(v4f*)&partA[((w * 5 + mt) * 16 + ml) * 16 + quad * 4] = acc[mt];
  __syncthreads();

  // ---------------- P4: reduce partials -> y1b bf16 [n][104] (alias x1T) ----------------
  u16* y1b = x1T;
#pragma unroll
  for (int it = 0; it < 5; ++it) {
    int e = t + it * 256;
    if (e < NO1 * 16) {
      int m = e >> 4, n = e & 15;
      float s = b1[m];
#pragma unroll
      for (int ww = 0; ww < 4; ++ww)
        s += partA[((ww * 5 + (m >> 4)) * 16 + n) * 16 + (m & 15)];
      y1b[n * 104 + m] = f2b(s);
    }
  }
  __syncthreads();

  // ---------------- P5: conv2 MFMA -> y2L [n][296] f32 (alias partials) ----------------
  {
    v8s bfr[3];
#pragma unroll
    for (int ks = 0; ks < 3; ++ks)
      bfr[ks] = *(v8s*)&y1b[ml * 104 + ks * 32 + quad * 8];
    const int mt0 = (w < 2) ? 5 * w : 10 + 4 * (w - 2);
    const int mtn = (w < 2) ? 5 : 4;
    for (int mi = 0; mi < mtn; ++mi) {
      const int mt = mt0 + mi;
      v4f a2 = (v4f){0.f, 0.f, 0.f, 0.f};
#pragma unroll
      for (int ks = 0; ks < 3; ++ks) {
        v8s af = *(const v8s*)&w2bf[(mt * 16 + ml) * 96 + ks * 32 + quad * 8];
        a2 = __builtin_amdgcn_mfma_f32_16x16x32_bf16(af, bfr[ks], a2, 0, 0, 0);
      }
      const int o0 = mt * 16 + quad * 4;
      const float4 bv = *(const float4*)(b2 + o0);
      a2[0] += bv.x; a2[1] += bv.y; a2[2] += bv.z; a2[3] += bv.w;
      *(v4f*)&y2L[ml * 296 + o0] = a2;
    }
  }
  __syncthreads();

  // ---------------- P6: softmax over k(9), 512 (g,nn,n) slots, in place ----------------
#pragma unroll
  for (int it = 0; it < 2; ++it) {
    int s2 = t + it * 256;
    int gg = s2 >> 6, rem = s2 & 63, nn = rem >> 4, n = rem & 15;
    float* bp = &y2L[n * 296 + gg * 36 + nn];
    float v9[9], m = -1e30f;
#pragma unroll
    for (int k = 0; k < 9; ++k) { v9[k] = bp[k * 4]; m = fmaxf(m, v9[k]); }
    float sum = 0.f;
#pragma unroll
    for (int k = 0; k < 9; ++k) { v9[k] = __expf(v9[k] - m); sum += v9[k]; }
    float inv = 1.f / sum;
#pragma unroll
    for (int k = 0; k < 9; ++k) bp[k * 4] = v9[k] * inv;
  }
  __syncthreads();

  // ---------------- P7: aggregation from register window ----------------
  float a0s[16], a1s[16], a2s[16], a3s[16];
#pragma unroll
  for (int n = 0; n < 16; ++n) {
    const v4f* wp = (const v4f*)&y2L[n * 296 + g * 36];   // 9 x float4 (k-major, nn inside)
    float a0 = 0.f, a1 = 0.f, a2v = 0.f, a3 = 0.f;
#pragma unroll
    for (int r = 0; r < 3; ++r) {
      float x0, x1, x2v;
      u32 ua = win_p[r][n >> 1], ub = win_p[r][(n >> 1) + 1];
      if ((n & 1) == 0) {
        x0  = __uint_as_float(ua << 16);
        x1  = __uint_as_float(ua & 0xffff0000u);
        x2v = __uint_as_float(ub << 16);
      } else {
        x0  = __uint_as_float(ua & 0xffff0000u);
        x1  = __uint_as_float(ub << 16);
        x2v = __uint_as_float(ub & 0xffff0000u);
      }
#pragma unroll
      for (int kj = 0; kj < 3; ++kj) {
        v4f wv = wp[r * 3 + kj];
        float x = (kj == 0) ? x0 : (kj == 1) ? x1 : x2v;
        a0  = fmaf(x, wv[0], a0);
        a1  = fmaf(x, wv[1], a1);
        a2v = fmaf(x, wv[2], a2v);
        a3  = fmaf(x, wv[3], a3);
      }
    }
    a0s[n] = a0; a1s[n] = a1; a2s[n] = a2v; a3s[n] = a3;
  }
  __syncthreads();   // y2L dead; lds becomes tile

  // ---------------- P8: per-di [x][c] transpose + fully-coalesced stores ----------------
  for (int di = 0; di < 2; ++di) {
#pragma unroll
    for (int n = 0; n < 16; ++n) {
      tile[(2 * n) * 258 + t]     = di ? a2s[n] : a0s[n];
      tile[(2 * n + 1) * 258 + t] = di ? a3s[n] : a1s[n];
    }
    __syncthreads();
#pragma unroll
    for (int it = 0; it < 8; ++it) {
      int f = t + it * 256;
      int c = f >> 3, fx = f & 7;
      int xcol = 32 * jt + fx * 4;
      if (xcol < W2D) {
        v4f v;
#pragma unroll
        for (int s = 0; s < 4; ++s) v[s] = tile[(fx * 4 + s) * 258 + c];
        *(v4f*)&out[((size_t)(b * CC + c) * H2 + (size_t)(2 * i + di)) * W2D + xcol] = v;
      }
    }
    if (di == 0) __syncthreads();
  }
}

extern "C" void kernel_launch(void* const* d_in, const int* in_sizes, int n_in,
                              void* d_out, int out_size, void* d_ws, size_t ws_size,
                              hipStream_t stream) {
  const float* in = (const float*)d_in[0];
  const float* W1 = (const float*)d_in[1];
  const float* b1 = (const float*)d_in[2];
  const float* W2 = (const float*)d_in[3];
  const float* b2 = (const float*)d_in[4];
  float* out = (float*)d_out;

  u16* w1bf = (u16*)d_ws;
  u16* w2bf = (u16*)((char*)d_ws + W2BF_OFF_B);

  const int B = in_sizes[0] / (CC * HH * WWID);

  kConvW<<<dim3((W1BF_ELEMS + NO2 * 96 + 255) / 256), 256, 0, stream>>>(W1, W2, w1bf, w2bf);
  dim3 grid(4, HH, B);
  kFused<<<grid, 256, 0, stream>>>(in, w1bf, b1, w2bf, b2, out);
}